// Round 8
// baseline (2997.856 us; speedup 1.0000x reference)
//
#include <hip/hip_runtime.h>
#include <math.h>

// Problem constants (reference: B,T,V,E,H = 32,512,32000,300,256)
#define BB 32
#define TT_LEN 512
#define EE 300
#define HH 256
#define G4 1024          // 4*H
#define CMAX 155         // int(round(0.3*512))+1
#define TRANS_T 10.0f    // TRANSITION/TEMP
#define NEGF -1.0e9f
#define INV_TEMP 100.0f  // 1/TEMP
#define AST_STRIDE 159   // slot-2 accesses predicated l<27 (max off 154)

typedef _Float16 half2v __attribute__((ext_vector_type(2)));
typedef _Float16 half8 __attribute__((ext_vector_type(8)));
typedef float f32x4 __attribute__((ext_vector_type(4)));

__device__ __forceinline__ float la(float x, float y) {
  float m = fmaxf(x, y);
  float d = fminf(x, y) - m;
  return m + __logf(1.0f + __expf(d));
}

__device__ __forceinline__ float sigm(float x) {
  return 1.0f / (1.0f + __expf(-x));
}

__device__ __forceinline__ float tanh_f(float x) {
  x = fminf(fmaxf(x, -15.f), 15.f);
  float e = __expf(2.f * x);
  return (e - 1.f) * __frcp_rn(e + 1.f);
}

__device__ __forceinline__ unsigned int packh(float a, float b) {
  half2v hp;
  hp.x = (_Float16)a;
  hp.y = (_Float16)b;
  return __builtin_bit_cast(unsigned int, hp);
}

__device__ __forceinline__ float2 h2f(unsigned int d) {
  half2v h = __builtin_bit_cast(half2v, d);
  return make_float2((float)h.x, (float)h.y);
}

__device__ __forceinline__ unsigned short f16b(float x) {
  _Float16 h = (_Float16)x;
  return __builtin_bit_cast(unsigned short, h);
}

// column mapping: gate-column n (0..1023) -> source column g*HH+u with
// g = gate type (i,f,g,o), u = unit. nb = [ug3][ug1][g2]: gate = nb&3,
// unit-group = nb>>2 (16 units).
__device__ __forceinline__ int nmap_col(int n) {
  int g = (n >> 4) & 3;
  int u = (n >> 7) * 32 + ((n >> 6) & 1) * 16 + (n & 15);
  return g * HH + u;
}

// ---------------- K0: weight prep ------------------------------------------
__global__ void prep_weights(const float* wi_f, const float* wi_b,
                             const float* wh_f, const float* wh_b,
                             const float* b_f, const float* b_b,
                             unsigned int* wi_frag, float* b_p, uint4* whn) {
  int idx = blockIdx.x * blockDim.x + threadIdx.x;
  int stride = gridDim.x * blockDim.x;
  for (int i = idx; i < 2 * 64 * 10 * 64 * 4; i += stride) {
    int u4 = i >> 2, d = i & 3;
    int lane = u4 & 63;
    int kk = (u4 >> 6) % 10;
    int nb = (u4 / 640) & 63;
    int dir = u4 / (640 * 64);
    int l15 = lane & 15, quad = lane >> 4;
    int col = nmap_col(nb * 16 + l15);
    int k0 = kk * 32 + quad * 8 + 2 * d;
    const float* src = dir ? wi_b : wi_f;
    float v0 = (k0 < EE) ? src[(size_t)k0 * G4 + col] : 0.0f;
    float v1 = (k0 + 1 < EE) ? src[(size_t)(k0 + 1) * G4 + col] : 0.0f;
    wi_frag[i] = packh(v0, v1);
  }
  for (int i = idx; i < 2 * 8 * 64 * 64; i += stride) {
    int lane = i & 63;
    int nb = (i >> 6) & 63;
    int kt = (i >> 12) & 7;
    int dir = i >> 15;
    int c = lane & 15, q = lane >> 4;
    int col = nmap_col(nb * 16 + c);
    int k0 = kt * 32 + q * 8;
    const float* src = dir ? wh_b : wh_f;
    uint4 o;
    o.x = packh(src[(size_t)(k0 + 0) * G4 + col], src[(size_t)(k0 + 1) * G4 + col]);
    o.y = packh(src[(size_t)(k0 + 2) * G4 + col], src[(size_t)(k0 + 3) * G4 + col]);
    o.z = packh(src[(size_t)(k0 + 4) * G4 + col], src[(size_t)(k0 + 5) * G4 + col]);
    o.w = packh(src[(size_t)(k0 + 6) * G4 + col], src[(size_t)(k0 + 7) * G4 + col]);
    whn[i] = o;  // i == ((dir*8+kt)*64+nb)*64+lane
  }
  for (int i = idx; i < 2 * G4; i += stride) {
    int dir = i / G4;
    int j = i % G4;
    const float* src = dir ? b_b : b_f;
    b_p[i] = src[nmap_col(j)];
  }
}

// ---------------- K_emb: gather -> A-fragment layout -----------------------
__global__ void gather_emb(const int* x, const float* embed, uint4* emb_frag) {
  int mblk = blockIdx.x;
  int t = threadIdx.x;
  int bg = mblk >> 9, tloc = mblk & 511;
  __shared__ int xs[16];
  if (t < 16) xs[t] = x[(bg * 16 + t) * TT_LEN + tloc];
  __syncthreads();
  for (int slot = t; slot < 640; slot += 256) {
    int kk = slot >> 6;
    int lane = slot & 63;
    int l15 = lane & 15, quad = lane >> 4;
    int row = xs[l15];
    int kbase = kk * 32 + quad * 8;
    const float* src = embed + (size_t)row * EE;
    float v[8];
#pragma unroll
    for (int e = 0; e < 8; ++e) v[e] = (kbase + e < EE) ? src[kbase + e] : 0.0f;
    uint4 o;
    o.x = packh(v[0], v[1]);
    o.y = packh(v[2], v[3]);
    o.z = packh(v[4], v[5]);
    o.w = packh(v[6], v[7]);
    emb_frag[(size_t)(mblk * 10 + kk) * 64 + lane] = o;
  }
}

// ---------------- K1: xg = emb @ wi^T + b, stored as f16 D-fragments -------
__global__ __launch_bounds__(256) void xg_mfma(
    const uint4* __restrict__ emb_frag, const uint4* __restrict__ wi_frag,
    const float* __restrict__ b_p, uint4* __restrict__ xg_frag) {
  int dir = blockIdx.z;
  int w = threadIdx.x >> 6;
  int lane = threadIdx.x & 63;
  int l15 = lane & 15;
  int mblk = blockIdx.y * 4 + w;

  const uint4* abase = emb_frag + (size_t)mblk * 10 * 64 + lane;
  f32x4 acc[4];
#pragma unroll
  for (int nt = 0; nt < 4; ++nt) acc[nt] = (f32x4){0.f, 0.f, 0.f, 0.f};

#pragma unroll
  for (int kk = 0; kk < 10; ++kk) {
    half8 a = __builtin_bit_cast(half8, abase[kk * 64]);
#pragma unroll
    for (int nt = 0; nt < 4; ++nt) {
      int nb = blockIdx.x * 4 + nt;
      half8 b = __builtin_bit_cast(
          half8, wi_frag[((size_t)(dir * 64 + nb) * 10 + kk) * 64 + lane]);
      acc[nt] = __builtin_amdgcn_mfma_f32_16x16x32_f16(a, b, acc[nt], 0, 0, 0);
    }
  }
#pragma unroll
  for (int ntp = 0; ntp < 2; ++ntp) {
    float bA = b_p[dir * G4 + (blockIdx.x * 4 + 2 * ntp) * 16 + l15];
    float bB = b_p[dir * G4 + (blockIdx.x * 4 + 2 * ntp + 1) * 16 + l15];
    f32x4 aA = acc[2 * ntp], aB = acc[2 * ntp + 1];
    uint4 o;
    o.x = packh(aA[0] + bA, aA[1] + bA);
    o.y = packh(aA[2] + bA, aA[3] + bA);
    o.z = packh(aB[0] + bB, aB[1] + bB);
    o.w = packh(aB[2] + bB, aB[3] + bB);
    xg_frag[((size_t)(dir * 1024 + mblk) * 32 + blockIdx.x * 2 + ntp) * 64 + lane] = o;
  }
}

// ---------------- K2: 512-thread MFMA LSTM ---------------------------------
// 4 blocks = (dir, bg), 512 threads = 8 waves. Each wave owns 8 n-tiles
// (nb = w*8..w*8+7): gates i,f,g,o of units u0=32w+c and u1=32w+16+c.
// REGISTER LAW (rounds 2-7): backend budgets 65536/blockDim dwords/thread
// (2-blocks-per-CU target); __launch_bounds__ 2nd arg acts like CUDA
// min-blocks. (512,1) -> 1 block/CU -> 256 regs/wave under that law (512
// under waves-per-EU reading; both >=256, so robust).
// Weight tiers sized to 256: kt0-2 in regs (24 frags = 96 dw), kt3-5
// streamed from L2 per step (staggered, <=64 dw in flight), kt6-7 in LDS
// (128 KB). h handoff: hfr A-fragment double buffer, one barrier/step
// (proven in round 7). Working set ~244 <= 256.
__global__ __launch_bounds__(512, 1) void lstm_mfma(
    const uint4* __restrict__ xg_frag, const uint4* __restrict__ whn,
    unsigned short* __restrict__ h16g) {
  int bid = blockIdx.x;  // dir*2 + bg
  int dir = bid >> 1, bg = bid & 1;
  int t = threadIdx.x;
  int lane = t & 63, w = t >> 6;  // w = 0..7
  int c = lane & 15, q = lane >> 4;

  __shared__ uint4 wlds[8192];              // 128 KB: kt6,7 as [nb*2+kt2][lane]
  __shared__ unsigned short hfr[2 * 4160];  // 16.25 KB A-frag double buffer

  const uint4* wsrc = whn + (size_t)dir * 32768 + 6 * 4096;
  for (int i = t; i < 8192; i += 512) {
    int l2 = i & 63, kt2 = (i >> 6) & 1, nb = i >> 7;
    wlds[(nb * 2 + kt2) * 64 + l2] = wsrc[kt2 * 4096 + nb * 64 + l2];
  }
  // zero buf1 (read at s=0; buf0 fully written at s=0 before s=1 reads)
  for (int i = t; i < 2080; i += 512) ((unsigned int*)hfr)[2080 + i] = 0;

  uint4 wreg[24];
#pragma unroll
  for (int kt = 0; kt < 3; ++kt)
#pragma unroll
    for (int j = 0; j < 8; ++j)
      wreg[kt * 8 + j] =
          whn[(size_t)dir * 32768 + kt * 4096 + (w * 8 + j) * 64 + lane];

  float cst[8];
#pragma unroll
  for (int i = 0; i < 8; ++i) cst[i] = 0.f;

  const uint4* w3p = whn + (size_t)dir * 32768 + 3 * 4096 + (w * 8) * 64 + lane;
  const uint4* w4p = w3p + 4096;
  const uint4* w5p = w3p + 8192;
  const uint4* xgp0 =
      xg_frag + ((size_t)(dir * 1024 + bg * 512) * 32 + w * 4) * 64 + lane;
  unsigned short* hgp = h16g + (size_t)dir * 4194304 +
                        (size_t)(w * 32 + c) * 32 + bg * 16 + 4 * q;
  // A-frag write offset for h(batch m=4q+r, unit u): u>>5 = w for both units;
  // off = w*1040 + (m + 16*((u>>3)&3))*16 + (u&7)*2; u1 adds 512 (ph*512).
  char* hfrb = (char*)hfr;
  const int wv0 = w * 1040 + (4 * q + 16 * (c >> 3)) * 16 + (c & 7) * 2;
  const int rv = lane * 16;

  __syncthreads();

#define MF(A, B, Dd) \
  Dd = __builtin_amdgcn_mfma_f32_16x16x32_f16(A, __builtin_bit_cast(half8, B), Dd, 0, 0, 0)

#define STEP(SS, BUF)                                                        \
  {                                                                          \
    int tt = dir ? (TT_LEN - 1 - (SS)) : (SS);                               \
    const uint4* xp = xgp0 + (size_t)tt * 2048;                              \
    uint4 s3[8], s4[8];                                                      \
    _Pragma("unroll") for (int j = 0; j < 8; ++j) s3[j] = w3p[j * 64];       \
    _Pragma("unroll") for (int j = 0; j < 8; ++j) s4[j] = w4p[j * 64];       \
    uint4 x0 = xp[0];                                                        \
    uint4 x1 = xp[64];                                                       \
    uint4 x2 = xp[128];                                                      \
    uint4 x3 = xp[192];                                                      \
    f32x4 D[8];                                                              \
    _Pragma("unroll") for (int j = 0; j < 8; ++j)                            \
        D[j] = (f32x4){0.f, 0.f, 0.f, 0.f};                                  \
    _Pragma("unroll") for (int kt = 0; kt < 3; ++kt) {                       \
      half8 A = *(const half8*)(hfrb + ((BUF) ^ 1) * 8320 + kt * 1040 + rv); \
      _Pragma("unroll") for (int j = 0; j < 8; ++j)                          \
          MF(A, wreg[kt * 8 + j], D[j]);                                     \
    }                                                                        \
    {                                                                        \
      half8 A = *(const half8*)(hfrb + ((BUF) ^ 1) * 8320 + 3 * 1040 + rv);  \
      _Pragma("unroll") for (int j = 0; j < 8; ++j) MF(A, s3[j], D[j]);      \
    }                                                                        \
    uint4 s5[8];                                                             \
    _Pragma("unroll") for (int j = 0; j < 8; ++j) s5[j] = w5p[j * 64];       \
    {                                                                        \
      half8 A = *(const half8*)(hfrb + ((BUF) ^ 1) * 8320 + 4 * 1040 + rv);  \
      _Pragma("unroll") for (int j = 0; j < 8; ++j) MF(A, s4[j], D[j]);      \
    }                                                                        \
    {                                                                        \
      half8 A = *(const half8*)(hfrb + ((BUF) ^ 1) * 8320 + 5 * 1040 + rv);  \
      _Pragma("unroll") for (int j = 0; j < 8; ++j) MF(A, s5[j], D[j]);      \
    }                                                                        \
    {                                                                        \
      half8 A = *(const half8*)(hfrb + ((BUF) ^ 1) * 8320 + 6 * 1040 + rv);  \
      _Pragma("unroll") for (int j = 0; j < 8; ++j)                          \
          MF(A, wlds[((w * 8 + j) * 2 + 0) * 64 + lane], D[j]);              \
    }                                                                        \
    {                                                                        \
      half8 A = *(const half8*)(hfrb + ((BUF) ^ 1) * 8320 + 7 * 1040 + rv);  \
      _Pragma("unroll") for (int j = 0; j < 8; ++j)                          \
          MF(A, wlds[((w * 8 + j) * 2 + 1) * 64 + lane], D[j]);              \
    }                                                                        \
    _Pragma("unroll") for (int ph = 0; ph < 2; ++ph) {                       \
      uint4 va = ph ? x2 : x0;                                               \
      uint4 vb = ph ? x3 : x1;                                               \
      float2 p0 = h2f(va.x), p1 = h2f(va.y), p2 = h2f(va.z), p3 = h2f(va.w); \
      float2 p4 = h2f(vb.x), p5 = h2f(vb.y), p6 = h2f(vb.z), p7 = h2f(vb.w); \
      float xi[4] = {p0.x, p0.y, p1.x, p1.y};                                \
      float xf[4] = {p2.x, p2.y, p3.x, p3.y};                                \
      float xgv[4] = {p4.x, p4.y, p5.x, p5.y};                               \
      float xo[4] = {p6.x, p6.y, p7.x, p7.y};                                \
      float hv[4];                                                           \
      _Pragma("unroll") for (int r = 0; r < 4; ++r) {                        \
        float I = sigm(D[ph * 4 + 0][r] + xi[r]);                            \
        float F = sigm(D[ph * 4 + 1][r] + xf[r]);                            \
        float G = tanh_f(D[ph * 4 + 2][r] + xgv[r]);                         \
        float O = sigm(D[ph * 4 + 3][r] + xo[r]);                            \
        float cn = F * cst[ph * 4 + r] + I * G;                              \
        cst[ph * 4 + r] = cn;                                                \
        hv[r] = O * tanh_f(cn);                                              \
        *(unsigned short*)(hfrb + (BUF)*8320 + wv0 + ph * 512 + r * 16) =    \
            f16b(hv[r]);                                                     \
      }                                                                      \
      uint2 pk;                                                              \
      pk.x = packh(hv[0], hv[1]);                                            \
      pk.y = packh(hv[2], hv[3]);                                            \
      *(uint2*)(hgp + ph * 512 + (size_t)tt * 8192) = pk;                    \
    }                                                                        \
    __syncthreads();                                                         \
  }

#pragma unroll 1
  for (int s = 0; s < TT_LEN; s += 2) {
    STEP(s, 0)
    STEP(s + 1, 1)
  }
#undef STEP
#undef MF
}

// ---------------- K3: scores = h . w_out (off the critical path) ----------
__global__ __launch_bounds__(64) void hscore(
    const unsigned short* __restrict__ h16g, const float* __restrict__ w_out,
    float* __restrict__ scores_part) {
  int dt = blockIdx.x;          // 0..1023 = dir*512 + t
  int dir = dt >> 9, tpos = dt & 511;
  int l = threadIdx.x;
  int b = l & 31, uh = l >> 5;
  const unsigned short* base =
      h16g + (((size_t)dir * 512 + tpos) * 256 + uh * 128) * 32 + b;
  const float* wo = w_out + dir * HH + uh * 128;
  float s = 0.f;
#pragma unroll 8
  for (int u = 0; u < 128; ++u) {
    _Float16 hv = __builtin_bit_cast(_Float16, base[(size_t)u * 32]);
    s += (float)hv * wo[u];
  }
  s += __shfl_down(s, 32, 64);
  if (uh == 0) scores_part[((size_t)dir * BB + b) * TT_LEN + tpos] = s;
}

// ---------------- K4: CRF fwd+bwd in PARALLEL WAVES ------------------------
__global__ __launch_bounds__(128) void dp3(const float* __restrict__ scores_part,
                                           const float* __restrict__ b_out,
                                           float* __restrict__ ast_g,
                                           float* __restrict__ bst_g,
                                           float* __restrict__ lzv) {
  int b = blockIdx.x;
  int l = threadIdx.x & 63;
  int w = threadIdx.x >> 6;
  const float* spf = scores_part + (size_t)b * TT_LEN;
  const float* spb = scores_part + (size_t)(BB + b) * TT_LEN;
  float bo = b_out[0];

  float ur[8];
#pragma unroll
  for (int i = 0; i < 8; ++i)
    ur[i] = (spf[i * 64 + l] + spb[i * 64 + l] + bo) * INV_TEMP;

  if (w == 0) {
    float* ast = ast_g + (size_t)b * TT_LEN * AST_STRIDE;
    int lm1 = (l + 63) & 63;
    float a0[3], a1[3];
    float u00 = __shfl(ur[0], 0, 64);
    a0[0] = (l == 1) ? (u00 + TRANS_T) : NEGF;
    a0[1] = NEGF;
    a0[2] = NEGF;
    a1[0] = (l == 0) ? 0.0f : NEGF;
    a1[1] = NEGF;
    a1[2] = NEGF;
    ast[l] = a0[0];
    ast[64 + l] = a0[1];
    if (l < 27) ast[128 + l] = a0[2];

#pragma unroll
    for (int ch = 0; ch < 8; ++ch) {
      float uc = ur[ch];
#pragma unroll 4
      for (int tt = (ch == 0 ? 1 : 0); tt < 64; ++tt) {
        int t = ch * 64 + tt;
        float u0t = __shfl(uc, tt, 64);
        float w0a = __shfl(a0[0], lm1, 64);
        float w1a = __shfl(a0[1], lm1, 64);
        float w2a = __shfl(a0[2], lm1, 64);
        float w0b = __shfl(a1[0], lm1, 64);
        float w1b = __shfl(a1[1], lm1, 64);
        float w2b = __shfl(a1[2], lm1, 64);
        float p0a = (l == 0) ? NEGF : w0a;
        float p1a = (l == 0) ? w0a : w1a;
        float p2a = (l == 0) ? w1a : w2a;
        float p0b = (l == 0) ? NEGF : w0b;
        float p1b = (l == 0) ? w0b : w1b;
        float p2b = (l == 0) ? w1b : w2b;
        float n00 = u0t + la(p0a + TRANS_T, p0b);
        float n01 = u0t + la(p1a + TRANS_T, p1b);
        float n02 = u0t + la(p2a + TRANS_T, p2b);
        float n10 = la(a0[0], a1[0]);
        float n11 = la(a0[1], a1[1]);
        float n12 = la(a0[2], a1[2]);
        a0[0] = n00;
        a0[1] = n01;
        a0[2] = (l < 27) ? n02 : NEGF;
        a1[0] = n10;
        a1[1] = n11;
        a1[2] = (l < 27) ? n12 : NEGF;
        float* astr = ast + (size_t)t * AST_STRIDE;
        astr[l] = a0[0];
        astr[64 + l] = a0[1];
        if (l < 27) astr[128 + l] = a0[2];
      }
    }
    float f00 = a0[0] + TRANS_T, f01 = a0[1] + TRANS_T, f02 = a0[2] + TRANS_T;
    float m = fmaxf(fmaxf(fmaxf(f00, f01), fmaxf(f02, a1[0])),
                    fmaxf(a1[1], a1[2]));
#pragma unroll
    for (int off = 32; off > 0; off >>= 1) m = fmaxf(m, __shfl_xor(m, off, 64));
    float es = __expf(f00 - m) + __expf(f01 - m) + __expf(f02 - m) +
               __expf(a1[0] - m) + __expf(a1[1] - m) + __expf(a1[2] - m);
#pragma unroll
    for (int off = 32; off > 0; off >>= 1) es += __shfl_xor(es, off, 64);
    if (l == 0) lzv[b] = m + __logf(es);
  } else {
    float* bst = bst_g + (size_t)b * TT_LEN * AST_STRIDE;
    int lp1 = (l + 1) & 63;
    float b0[3], b1[3];
    b0[0] = TRANS_T;
    b0[1] = TRANS_T;
    b0[2] = (l < 27) ? TRANS_T : NEGF;
    b1[0] = 0.0f;
    b1[1] = 0.0f;
    b1[2] = (l < 27) ? 0.0f : NEGF;
    {
      float* br = bst + (size_t)(TT_LEN - 1) * AST_STRIDE;
      br[l] = b0[0];
      br[64 + l] = b0[1];
      if (l < 27) br[128 + l] = b0[2];
    }
#pragma unroll
    for (int ch = 7; ch >= 0; --ch) {
      float uc = ur[ch];
#pragma unroll 4
      for (int tt = 63; tt >= (ch == 0 ? 1 : 0); --tt) {
        int t = ch * 64 + tt;
        float u0t = __shfl(uc, tt, 64);
        float w0 = __shfl(b0[0], lp1, 64);
        float w1 = __shfl(b0[1], lp1, 64);
        float w2 = __shfl(b0[2], lp1, 64);
        float x2 = (l == 63) ? NEGF : w2;
        float x1 = (l == 63) ? w2 : w1;
        float x0 = (l == 63) ? w1 : w0;
        float nb00 = la(u0t + TRANS_T + x0, b1[0]);
        float nb01 = la(u0t + TRANS_T + x1, b1[1]);
        float nb02 = la(u0t + TRANS_T + x2, b1[2]);
        float nb10 = la(u0t + x0, b1[0]);
        float nb11 = la(u0t + x1, b1[1]);
        float nb12 = la(u0t + x2, b1[2]);
        b0[0] = nb00;
        b0[1] = nb01;
        b0[2] = (l < 27) ? nb02 : NEGF;
        b1[0] = nb10;
        b1[1] = nb11;
        b1[2] = (l < 27) ? nb12 : NEGF;
        float* br = bst + (size_t)(t - 1) * AST_STRIDE;
        br[l] = b0[0];
        br[64 + l] = b0[1];
        if (l < 27) br[128 + l] = b0[2];
      }
    }
  }
}

// ---------------- K5: marginals, fully parallel ----------------------------
__global__ __launch_bounds__(256) void marg(const float* __restrict__ ast_g,
                                            const float* __restrict__ bst_g,
                                            const float* __restrict__ lzv,
                                            float* __restrict__ out) {
  int row = blockIdx.x * 4 + (threadIdx.x >> 6);
  int l = threadIdx.x & 63;
  int b = row >> 9;
  const float* ar = ast_g + (size_t)row * AST_STRIDE;
  const float* br = bst_g + (size_t)row * AST_STRIDE;
  float lz = lzv[b];
  float s = __expf(ar[l] + br[l] - lz) + __expf(ar[64 + l] + br[64 + l] - lz) +
            ((l < 27) ? __expf(ar[128 + l] + br[128 + l] - lz) : 0.0f);
#pragma unroll
  for (int off = 32; off > 0; off >>= 1) s += __shfl_xor(s, off, 64);
  if (l == 0) out[row] = s;
}

// ---------------------------------------------------------------------------
extern "C" void kernel_launch(void* const* d_in, const int* in_sizes, int n_in,
                              void* d_out, int out_size, void* d_ws, size_t ws_size,
                              hipStream_t stream) {
  const int* x = (const int*)d_in[0];
  const float* embed = (const float*)d_in[3];
  const float* wi_f = (const float*)d_in[4];
  const float* wh_f = (const float*)d_in[5];
  const float* bf = (const float*)d_in[6];
  const float* wi_b = (const float*)d_in[7];
  const float* wh_b = (const float*)d_in[8];
  const float* bbias = (const float*)d_in[9];
  const float* w_out = (const float*)d_in[10];
  const float* b_out = (const float*)d_in[11];

  float* ws = (float*)d_ws;
  float* b_p = ws;                                            // 2048 f32
  unsigned int* wi_frag = (unsigned int*)(b_p + 2 * G4);      // 327680 dw
  uint4* whn = (uint4*)(wi_frag + 2 * 64 * 10 * 64 * 4);      // 65536 uint4
  uint4* emb_frag = whn + 65536;                              // 655360 uint4
  uint4* xg_frag = emb_frag + 655360;                         // 4194304 uint4
  unsigned short* h16g = (unsigned short*)(xg_frag + 4194304);  // 8388608 us
  float* scores_part = (float*)(h16g + 8388608);              // 32768 f32
  float* lzv = scores_part + 2 * BB * TT_LEN;                 // 32 (+pad)
  float* ast_g = lzv + 64;                                    // 32*512*159 f32
  // bst aliases emb_frag (dead after xg_mfma): 10.42 MB fits in 10.49 MB
  float* bst_g = (float*)emb_frag;
  float* outp = (float*)d_out;

  prep_weights<<<256, 256, 0, stream>>>(wi_f, wi_b, wh_f, wh_b, bf, bbias,
                                        wi_frag, b_p, whn);
  gather_emb<<<(BB * TT_LEN) / 16, 256, 0, stream>>>(x, embed, emb_frag);
  dim3 g1(16, 256, 2);
  xg_mfma<<<g1, 256, 0, stream>>>(emb_frag, (const uint4*)wi_frag, b_p, xg_frag);
  lstm_mfma<<<4, 512, 0, stream>>>(xg_frag, whn, h16g);
  hscore<<<2 * TT_LEN, 64, 0, stream>>>(h16g, w_out, scores_part);
  dp3<<<BB, 128, 0, stream>>>(scores_part, b_out, ast_g, bst_g, lzv);
  marg<<<(BB * TT_LEN) / 4, 256, 0, stream>>>(ast_g, bst_g, lzv, outp);
}

// Round 9
// 2945.228 us; speedup vs baseline: 1.0179x; 1.0179x over previous
//
#include <hip/hip_runtime.h>
#include <math.h>

// Problem constants (reference: B,T,V,E,H = 32,512,32000,300,256)
#define BB 32
#define TT_LEN 512
#define EE 300
#define HH 256
#define G4 1024          // 4*H
#define CMAX 155         // int(round(0.3*512))+1
#define TRANS_T 10.0f    // TRANSITION/TEMP
#define NEGF -1.0e9f
#define INV_TEMP 100.0f  // 1/TEMP
#define AST_STRIDE 159   // slot-2 accesses predicated l<27 (max off 154)

typedef _Float16 half2v __attribute__((ext_vector_type(2)));
typedef _Float16 half8 __attribute__((ext_vector_type(8)));
typedef float f32x4 __attribute__((ext_vector_type(4)));

__device__ __forceinline__ float la(float x, float y) {
  float m = fmaxf(x, y);
  float d = fminf(x, y) - m;
  return m + __logf(1.0f + __expf(d));
}

__device__ __forceinline__ float sigm(float x) {
  return 1.0f / (1.0f + __expf(-x));
}

__device__ __forceinline__ float tanh_f(float x) {
  x = fminf(fmaxf(x, -15.f), 15.f);
  float e = __expf(2.f * x);
  return (e - 1.f) * __frcp_rn(e + 1.f);
}

__device__ __forceinline__ unsigned int packh(float a, float b) {
  half2v hp;
  hp.x = (_Float16)a;
  hp.y = (_Float16)b;
  return __builtin_bit_cast(unsigned int, hp);
}

__device__ __forceinline__ float2 h2f(unsigned int d) {
  half2v h = __builtin_bit_cast(half2v, d);
  return make_float2((float)h.x, (float)h.y);
}

__device__ __forceinline__ unsigned short f16b(float x) {
  _Float16 h = (_Float16)x;
  return __builtin_bit_cast(unsigned short, h);
}

// column mapping: gate-column n (0..1023) -> source column g*HH+u with
// g = gate type (i,f,g,o), u = unit. nb = [ug3][ug1][g2]: gate = nb&3,
// unit-group = nb>>2 (16 units).
__device__ __forceinline__ int nmap_col(int n) {
  int g = (n >> 4) & 3;
  int u = (n >> 7) * 32 + ((n >> 6) & 1) * 16 + (n & 15);
  return g * HH + u;
}

// ---------------- K0: weight prep ------------------------------------------
__global__ void prep_weights(const float* wi_f, const float* wi_b,
                             const float* wh_f, const float* wh_b,
                             const float* b_f, const float* b_b,
                             unsigned int* wi_frag, float* b_p, uint4* whn) {
  int idx = blockIdx.x * blockDim.x + threadIdx.x;
  int stride = gridDim.x * blockDim.x;
  for (int i = idx; i < 2 * 64 * 10 * 64 * 4; i += stride) {
    int u4 = i >> 2, d = i & 3;
    int lane = u4 & 63;
    int kk = (u4 >> 6) % 10;
    int nb = (u4 / 640) & 63;
    int dir = u4 / (640 * 64);
    int l15 = lane & 15, quad = lane >> 4;
    int col = nmap_col(nb * 16 + l15);
    int k0 = kk * 32 + quad * 8 + 2 * d;
    const float* src = dir ? wi_b : wi_f;
    float v0 = (k0 < EE) ? src[(size_t)k0 * G4 + col] : 0.0f;
    float v1 = (k0 + 1 < EE) ? src[(size_t)(k0 + 1) * G4 + col] : 0.0f;
    wi_frag[i] = packh(v0, v1);
  }
  for (int i = idx; i < 2 * 8 * 64 * 64; i += stride) {
    int lane = i & 63;
    int nb = (i >> 6) & 63;
    int kt = (i >> 12) & 7;
    int dir = i >> 15;
    int c = lane & 15, q = lane >> 4;
    int col = nmap_col(nb * 16 + c);
    int k0 = kt * 32 + q * 8;
    const float* src = dir ? wh_b : wh_f;
    uint4 o;
    o.x = packh(src[(size_t)(k0 + 0) * G4 + col], src[(size_t)(k0 + 1) * G4 + col]);
    o.y = packh(src[(size_t)(k0 + 2) * G4 + col], src[(size_t)(k0 + 3) * G4 + col]);
    o.z = packh(src[(size_t)(k0 + 4) * G4 + col], src[(size_t)(k0 + 5) * G4 + col]);
    o.w = packh(src[(size_t)(k0 + 6) * G4 + col], src[(size_t)(k0 + 7) * G4 + col]);
    whn[i] = o;  // i == ((dir*8+kt)*64+nb)*64+lane
  }
  for (int i = idx; i < 2 * G4; i += stride) {
    int dir = i / G4;
    int j = i % G4;
    const float* src = dir ? b_b : b_f;
    b_p[i] = src[nmap_col(j)];
  }
}

// ---------------- K_emb: gather -> A-fragment layout -----------------------
__global__ void gather_emb(const int* x, const float* embed, uint4* emb_frag) {
  int mblk = blockIdx.x;
  int t = threadIdx.x;
  int bg = mblk >> 9, tloc = mblk & 511;
  __shared__ int xs[16];
  if (t < 16) xs[t] = x[(bg * 16 + t) * TT_LEN + tloc];
  __syncthreads();
  for (int slot = t; slot < 640; slot += 256) {
    int kk = slot >> 6;
    int lane = slot & 63;
    int l15 = lane & 15, quad = lane >> 4;
    int row = xs[l15];
    int kbase = kk * 32 + quad * 8;
    const float* src = embed + (size_t)row * EE;
    float v[8];
#pragma unroll
    for (int e = 0; e < 8; ++e) v[e] = (kbase + e < EE) ? src[kbase + e] : 0.0f;
    uint4 o;
    o.x = packh(v[0], v[1]);
    o.y = packh(v[2], v[3]);
    o.z = packh(v[4], v[5]);
    o.w = packh(v[6], v[7]);
    emb_frag[(size_t)(mblk * 10 + kk) * 64 + lane] = o;
  }
}

// ---------------- K1: xg = emb @ wi^T + b, stored as f16 D-fragments -------
__global__ __launch_bounds__(256) void xg_mfma(
    const uint4* __restrict__ emb_frag, const uint4* __restrict__ wi_frag,
    const float* __restrict__ b_p, uint4* __restrict__ xg_frag) {
  int dir = blockIdx.z;
  int w = threadIdx.x >> 6;
  int lane = threadIdx.x & 63;
  int l15 = lane & 15;
  int mblk = blockIdx.y * 4 + w;

  const uint4* abase = emb_frag + (size_t)mblk * 10 * 64 + lane;
  f32x4 acc[4];
#pragma unroll
  for (int nt = 0; nt < 4; ++nt) acc[nt] = (f32x4){0.f, 0.f, 0.f, 0.f};

#pragma unroll
  for (int kk = 0; kk < 10; ++kk) {
    half8 a = __builtin_bit_cast(half8, abase[kk * 64]);
#pragma unroll
    for (int nt = 0; nt < 4; ++nt) {
      int nb = blockIdx.x * 4 + nt;
      half8 b = __builtin_bit_cast(
          half8, wi_frag[((size_t)(dir * 64 + nb) * 10 + kk) * 64 + lane]);
      acc[nt] = __builtin_amdgcn_mfma_f32_16x16x32_f16(a, b, acc[nt], 0, 0, 0);
    }
  }
#pragma unroll
  for (int ntp = 0; ntp < 2; ++ntp) {
    float bA = b_p[dir * G4 + (blockIdx.x * 4 + 2 * ntp) * 16 + l15];
    float bB = b_p[dir * G4 + (blockIdx.x * 4 + 2 * ntp + 1) * 16 + l15];
    f32x4 aA = acc[2 * ntp], aB = acc[2 * ntp + 1];
    uint4 o;
    o.x = packh(aA[0] + bA, aA[1] + bA);
    o.y = packh(aA[2] + bA, aA[3] + bA);
    o.z = packh(aB[0] + bB, aB[1] + bB);
    o.w = packh(aB[2] + bB, aB[3] + bB);
    xg_frag[((size_t)(dir * 1024 + mblk) * 32 + blockIdx.x * 2 + ntp) * 64 + lane] = o;
  }
}

// ---------------- K2: 512-thread MFMA LSTM, zero-spill streaming -----------
// 4 blocks = (dir, bg), 512 threads = 8 waves. Wave w owns nb = w*8..w*8+7.
// ROUNDS 2-8 LESSON: allocator grants exactly 65536/blockDim regs (128 here)
// no matter what launch bounds/attrs say; every design with working set >128
// spilled (~10k extra VALU cyc/step, VALUBusy 84%). This design FITS 128:
// NO register-resident weights. kt6,7 from LDS (128 KB); kt0-5 (384 KB/step)
// streamed from L2 through a 2-chunk (sA/sB, 32 dw) rotating pipeline,
// reissued one kt ahead; kt0 chunks prefetched across the step boundary
// (weight addresses are step-invariant -> L2-resident). LDS kt6/kt7 MFMA
// clusters interleave after kt0/kt1 to pad L2 latency. Peak regs ~110.
// hfr A-frag double buffer + one barrier/step proven in r7/r8.
__global__ __launch_bounds__(512, 1) void lstm_mfma(
    const uint4* __restrict__ xg_frag, const uint4* __restrict__ whn,
    unsigned short* __restrict__ h16g) {
  int bid = blockIdx.x;  // dir*2 + bg
  int dir = bid >> 1, bg = bid & 1;
  int t = threadIdx.x;
  int lane = t & 63, w = t >> 6;  // w = 0..7
  int c = lane & 15, q = lane >> 4;

  __shared__ uint4 wlds[8192];              // 128 KB: kt6,7 as [nb*2+kt2][lane]
  __shared__ unsigned short hfr[2 * 4160];  // 16.25 KB A-frag double buffer

  const uint4* wsrc = whn + (size_t)dir * 32768 + 6 * 4096;
  for (int i = t; i < 8192; i += 512) {
    int l2 = i & 63, kt2 = (i >> 6) & 1, nb = i >> 7;
    wlds[(nb * 2 + kt2) * 64 + l2] = wsrc[kt2 * 4096 + nb * 64 + l2];
  }
  // zero buf1 (read at s=0; buf0 fully written at s=0 before s=1 reads)
  for (int i = t; i < 2080; i += 512) ((unsigned int*)hfr)[2080 + i] = 0;

  float cst[8];
#pragma unroll
  for (int i = 0; i < 8; ++i) cst[i] = 0.f;

  // stream base: frag (kt, j) at wkp[kt*4096 + j*64]
  const uint4* wkp = whn + (size_t)dir * 32768 + (w * 8) * 64 + lane;
  const uint4* xgp0 =
      xg_frag + ((size_t)(dir * 1024 + bg * 512) * 32 + w * 4) * 64 + lane;
  unsigned short* hgp = h16g + (size_t)dir * 4194304 +
                        (size_t)(w * 32 + c) * 32 + bg * 16 + 4 * q;
  char* hfrb = (char*)hfr;
  const int wv0 = w * 1040 + (4 * q + 16 * (c >> 3)) * 16 + (c & 7) * 2;
  const int rv = lane * 16;

  // cross-step prefetch: kt0 chunks a (j0-3) and b (j4-7)
  uint4 sA0 = wkp[0], sA1 = wkp[64], sA2 = wkp[128], sA3 = wkp[192];
  uint4 sB0 = wkp[256], sB1 = wkp[320], sB2 = wkp[384], sB3 = wkp[448];

  __syncthreads();

#define MF(A, B, Dd) \
  Dd = __builtin_amdgcn_mfma_f32_16x16x32_f16(A, __builtin_bit_cast(half8, B), Dd, 0, 0, 0)

// consume sA/sB for kt, reissue for kt+1 (NXT = (kt+1)*4096, or 0 wrap)
#define KT_STREAM(kt, NXT, BUFP)                                             \
  {                                                                          \
    half8 A = *(const half8*)(hfrb + (BUFP)*8320 + (kt)*1040 + rv);          \
    MF(A, sA0, D[0]);                                                        \
    MF(A, sA1, D[1]);                                                        \
    MF(A, sA2, D[2]);                                                        \
    MF(A, sA3, D[3]);                                                        \
    sA0 = wkp[(NXT) + 0];                                                    \
    sA1 = wkp[(NXT) + 64];                                                   \
    sA2 = wkp[(NXT) + 128];                                                  \
    sA3 = wkp[(NXT) + 192];                                                  \
    MF(A, sB0, D[4]);                                                        \
    MF(A, sB1, D[5]);                                                        \
    MF(A, sB2, D[6]);                                                        \
    MF(A, sB3, D[7]);                                                        \
    sB0 = wkp[(NXT) + 256];                                                  \
    sB1 = wkp[(NXT) + 320];                                                  \
    sB2 = wkp[(NXT) + 384];                                                  \
    sB3 = wkp[(NXT) + 448];                                                  \
  }

#define KT_LDS(kt, BUFP)                                                     \
  {                                                                          \
    half8 A = *(const half8*)(hfrb + (BUFP)*8320 + (kt)*1040 + rv);          \
    MF(A, wlds[((w * 8 + 0) * 2 + ((kt)-6)) * 64 + lane], D[0]);             \
    MF(A, wlds[((w * 8 + 1) * 2 + ((kt)-6)) * 64 + lane], D[1]);             \
    MF(A, wlds[((w * 8 + 2) * 2 + ((kt)-6)) * 64 + lane], D[2]);             \
    MF(A, wlds[((w * 8 + 3) * 2 + ((kt)-6)) * 64 + lane], D[3]);             \
    MF(A, wlds[((w * 8 + 4) * 2 + ((kt)-6)) * 64 + lane], D[4]);             \
    MF(A, wlds[((w * 8 + 5) * 2 + ((kt)-6)) * 64 + lane], D[5]);             \
    MF(A, wlds[((w * 8 + 6) * 2 + ((kt)-6)) * 64 + lane], D[6]);             \
    MF(A, wlds[((w * 8 + 7) * 2 + ((kt)-6)) * 64 + lane], D[7]);             \
  }

#define STEP(SS, BUF)                                                        \
  {                                                                          \
    int tt = dir ? (TT_LEN - 1 - (SS)) : (SS);                               \
    const uint4* xp = xgp0 + (size_t)tt * 2048;                              \
    uint4 x0 = xp[0];                                                        \
    uint4 x1 = xp[64];                                                       \
    uint4 x2 = xp[128];                                                      \
    uint4 x3 = xp[192];                                                      \
    f32x4 D[8];                                                              \
    _Pragma("unroll") for (int j = 0; j < 8; ++j)                            \
        D[j] = (f32x4){0.f, 0.f, 0.f, 0.f};                                  \
    KT_STREAM(0, 4096, (BUF) ^ 1)                                            \
    KT_LDS(6, (BUF) ^ 1)                                                     \
    KT_STREAM(1, 8192, (BUF) ^ 1)                                            \
    KT_LDS(7, (BUF) ^ 1)                                                     \
    KT_STREAM(2, 12288, (BUF) ^ 1)                                           \
    KT_STREAM(3, 16384, (BUF) ^ 1)                                           \
    KT_STREAM(4, 20480, (BUF) ^ 1)                                           \
    KT_STREAM(5, 0, (BUF) ^ 1)                                               \
    _Pragma("unroll") for (int ph = 0; ph < 2; ++ph) {                       \
      uint4 va = ph ? x2 : x0;                                               \
      uint4 vb = ph ? x3 : x1;                                               \
      float2 p0 = h2f(va.x), p1 = h2f(va.y), p2 = h2f(va.z), p3 = h2f(va.w); \
      float2 p4 = h2f(vb.x), p5 = h2f(vb.y), p6 = h2f(vb.z), p7 = h2f(vb.w); \
      float xi[4] = {p0.x, p0.y, p1.x, p1.y};                                \
      float xf[4] = {p2.x, p2.y, p3.x, p3.y};                                \
      float xgv[4] = {p4.x, p4.y, p5.x, p5.y};                               \
      float xo[4] = {p6.x, p6.y, p7.x, p7.y};                                \
      float hv[4];                                                           \
      _Pragma("unroll") for (int r = 0; r < 4; ++r) {                        \
        float I = sigm(D[ph * 4 + 0][r] + xi[r]);                            \
        float F = sigm(D[ph * 4 + 1][r] + xf[r]);                            \
        float G = tanh_f(D[ph * 4 + 2][r] + xgv[r]);                         \
        float O = sigm(D[ph * 4 + 3][r] + xo[r]);                            \
        float cn = F * cst[ph * 4 + r] + I * G;                              \
        cst[ph * 4 + r] = cn;                                                \
        hv[r] = O * tanh_f(cn);                                              \
        *(unsigned short*)(hfrb + (BUF)*8320 + wv0 + ph * 512 + r * 16) =    \
            f16b(hv[r]);                                                     \
      }                                                                      \
      uint2 pk;                                                              \
      pk.x = packh(hv[0], hv[1]);                                            \
      pk.y = packh(hv[2], hv[3]);                                            \
      *(uint2*)(hgp + ph * 512 + (size_t)tt * 8192) = pk;                    \
    }                                                                        \
    __syncthreads();                                                         \
  }

#pragma unroll 1
  for (int s = 0; s < TT_LEN; s += 2) {
    STEP(s, 0)
    STEP(s + 1, 1)
  }
#undef STEP
#undef KT_LDS
#undef KT_STREAM
#undef MF
}

// ---------------- K3: scores = h . w_out (off the critical path) ----------
__global__ __launch_bounds__(64) void hscore(
    const unsigned short* __restrict__ h16g, const float* __restrict__ w_out,
    float* __restrict__ scores_part) {
  int dt = blockIdx.x;          // 0..1023 = dir*512 + t
  int dir = dt >> 9, tpos = dt & 511;
  int l = threadIdx.x;
  int b = l & 31, uh = l >> 5;
  const unsigned short* base =
      h16g + (((size_t)dir * 512 + tpos) * 256 + uh * 128) * 32 + b;
  const float* wo = w_out + dir * HH + uh * 128;
  float s = 0.f;
#pragma unroll 8
  for (int u = 0; u < 128; ++u) {
    _Float16 hv = __builtin_bit_cast(_Float16, base[(size_t)u * 32]);
    s += (float)hv * wo[u];
  }
  s += __shfl_down(s, 32, 64);
  if (uh == 0) scores_part[((size_t)dir * BB + b) * TT_LEN + tpos] = s;
}

// ---------------- K4: CRF fwd+bwd in PARALLEL WAVES ------------------------
__global__ __launch_bounds__(128) void dp3(const float* __restrict__ scores_part,
                                           const float* __restrict__ b_out,
                                           float* __restrict__ ast_g,
                                           float* __restrict__ bst_g,
                                           float* __restrict__ lzv) {
  int b = blockIdx.x;
  int l = threadIdx.x & 63;
  int w = threadIdx.x >> 6;
  const float* spf = scores_part + (size_t)b * TT_LEN;
  const float* spb = scores_part + (size_t)(BB + b) * TT_LEN;
  float bo = b_out[0];

  float ur[8];
#pragma unroll
  for (int i = 0; i < 8; ++i)
    ur[i] = (spf[i * 64 + l] + spb[i * 64 + l] + bo) * INV_TEMP;

  if (w == 0) {
    float* ast = ast_g + (size_t)b * TT_LEN * AST_STRIDE;
    int lm1 = (l + 63) & 63;
    float a0[3], a1[3];
    float u00 = __shfl(ur[0], 0, 64);
    a0[0] = (l == 1) ? (u00 + TRANS_T) : NEGF;
    a0[1] = NEGF;
    a0[2] = NEGF;
    a1[0] = (l == 0) ? 0.0f : NEGF;
    a1[1] = NEGF;
    a1[2] = NEGF;
    ast[l] = a0[0];
    ast[64 + l] = a0[1];
    if (l < 27) ast[128 + l] = a0[2];

#pragma unroll
    for (int ch = 0; ch < 8; ++ch) {
      float uc = ur[ch];
#pragma unroll 4
      for (int tt = (ch == 0 ? 1 : 0); tt < 64; ++tt) {
        int t = ch * 64 + tt;
        float u0t = __shfl(uc, tt, 64);
        float w0a = __shfl(a0[0], lm1, 64);
        float w1a = __shfl(a0[1], lm1, 64);
        float w2a = __shfl(a0[2], lm1, 64);
        float w0b = __shfl(a1[0], lm1, 64);
        float w1b = __shfl(a1[1], lm1, 64);
        float w2b = __shfl(a1[2], lm1, 64);
        float p0a = (l == 0) ? NEGF : w0a;
        float p1a = (l == 0) ? w0a : w1a;
        float p2a = (l == 0) ? w1a : w2a;
        float p0b = (l == 0) ? NEGF : w0b;
        float p1b = (l == 0) ? w0b : w1b;
        float p2b = (l == 0) ? w1b : w2b;
        float n00 = u0t + la(p0a + TRANS_T, p0b);
        float n01 = u0t + la(p1a + TRANS_T, p1b);
        float n02 = u0t + la(p2a + TRANS_T, p2b);
        float n10 = la(a0[0], a1[0]);
        float n11 = la(a0[1], a1[1]);
        float n12 = la(a0[2], a1[2]);
        a0[0] = n00;
        a0[1] = n01;
        a0[2] = (l < 27) ? n02 : NEGF;
        a1[0] = n10;
        a1[1] = n11;
        a1[2] = (l < 27) ? n12 : NEGF;
        float* astr = ast + (size_t)t * AST_STRIDE;
        astr[l] = a0[0];
        astr[64 + l] = a0[1];
        if (l < 27) astr[128 + l] = a0[2];
      }
    }
    float f00 = a0[0] + TRANS_T, f01 = a0[1] + TRANS_T, f02 = a0[2] + TRANS_T;
    float m = fmaxf(fmaxf(fmaxf(f00, f01), fmaxf(f02, a1[0])),
                    fmaxf(a1[1], a1[2]));
#pragma unroll
    for (int off = 32; off > 0; off >>= 1) m = fmaxf(m, __shfl_xor(m, off, 64));
    float es = __expf(f00 - m) + __expf(f01 - m) + __expf(f02 - m) +
               __expf(a1[0] - m) + __expf(a1[1] - m) + __expf(a1[2] - m);
#pragma unroll
    for (int off = 32; off > 0; off >>= 1) es += __shfl_xor(es, off, 64);
    if (l == 0) lzv[b] = m + __logf(es);
  } else {
    float* bst = bst_g + (size_t)b * TT_LEN * AST_STRIDE;
    int lp1 = (l + 1) & 63;
    float b0[3], b1[3];
    b0[0] = TRANS_T;
    b0[1] = TRANS_T;
    b0[2] = (l < 27) ? TRANS_T : NEGF;
    b1[0] = 0.0f;
    b1[1] = 0.0f;
    b1[2] = (l < 27) ? 0.0f : NEGF;
    {
      float* br = bst + (size_t)(TT_LEN - 1) * AST_STRIDE;
      br[l] = b0[0];
      br[64 + l] = b0[1];
      if (l < 27) br[128 + l] = b0[2];
    }
#pragma unroll
    for (int ch = 7; ch >= 0; --ch) {
      float uc = ur[ch];
#pragma unroll 4
      for (int tt = 63; tt >= (ch == 0 ? 1 : 0); --tt) {
        int t = ch * 64 + tt;
        float u0t = __shfl(uc, tt, 64);
        float w0 = __shfl(b0[0], lp1, 64);
        float w1 = __shfl(b0[1], lp1, 64);
        float w2 = __shfl(b0[2], lp1, 64);
        float x2 = (l == 63) ? NEGF : w2;
        float x1 = (l == 63) ? w2 : w1;
        float x0 = (l == 63) ? w1 : w0;
        float nb00 = la(u0t + TRANS_T + x0, b1[0]);
        float nb01 = la(u0t + TRANS_T + x1, b1[1]);
        float nb02 = la(u0t + TRANS_T + x2, b1[2]);
        float nb10 = la(u0t + x0, b1[0]);
        float nb11 = la(u0t + x1, b1[1]);
        float nb12 = la(u0t + x2, b1[2]);
        b0[0] = nb00;
        b0[1] = nb01;
        b0[2] = (l < 27) ? nb02 : NEGF;
        b1[0] = nb10;
        b1[1] = nb11;
        b1[2] = (l < 27) ? nb12 : NEGF;
        float* br = bst + (size_t)(t - 1) * AST_STRIDE;
        br[l] = b0[0];
        br[64 + l] = b0[1];
        if (l < 27) br[128 + l] = b0[2];
      }
    }
  }
}

// ---------------- K5: marginals, fully parallel ----------------------------
__global__ __launch_bounds__(256) void marg(const float* __restrict__ ast_g,
                                            const float* __restrict__ bst_g,
                                            const float* __restrict__ lzv,
                                            float* __restrict__ out) {
  int row = blockIdx.x * 4 + (threadIdx.x >> 6);
  int l = threadIdx.x & 63;
  int b = row >> 9;
  const float* ar = ast_g + (size_t)row * AST_STRIDE;
  const float* br = bst_g + (size_t)row * AST_STRIDE;
  float lz = lzv[b];
  float s = __expf(ar[l] + br[l] - lz) + __expf(ar[64 + l] + br[64 + l] - lz) +
            ((l < 27) ? __expf(ar[128 + l] + br[128 + l] - lz) : 0.0f);
#pragma unroll
  for (int off = 32; off > 0; off >>= 1) s += __shfl_xor(s, off, 64);
  if (l == 0) out[row] = s;
}

// ---------------------------------------------------------------------------
extern "C" void kernel_launch(void* const* d_in, const int* in_sizes, int n_in,
                              void* d_out, int out_size, void* d_ws, size_t ws_size,
                              hipStream_t stream) {
  const int* x = (const int*)d_in[0];
  const float* embed = (const float*)d_in[3];
  const float* wi_f = (const float*)d_in[4];
  const float* wh_f = (const float*)d_in[5];
  const float* bf = (const float*)d_in[6];
  const float* wi_b = (const float*)d_in[7];
  const float* wh_b = (const float*)d_in[8];
  const float* bbias = (const float*)d_in[9];
  const float* w_out = (const float*)d_in[10];
  const float* b_out = (const float*)d_in[11];

  float* ws = (float*)d_ws;
  float* b_p = ws;                                            // 2048 f32
  unsigned int* wi_frag = (unsigned int*)(b_p + 2 * G4);      // 327680 dw
  uint4* whn = (uint4*)(wi_frag + 2 * 64 * 10 * 64 * 4);      // 65536 uint4
  uint4* emb_frag = whn + 65536;                              // 655360 uint4
  uint4* xg_frag = emb_frag + 655360;                         // 4194304 uint4
  unsigned short* h16g = (unsigned short*)(xg_frag + 4194304);  // 8388608 us
  float* scores_part = (float*)(h16g + 8388608);              // 32768 f32
  float* lzv = scores_part + 2 * BB * TT_LEN;                 // 32 (+pad)
  float* ast_g = lzv + 64;                                    // 32*512*159 f32
  // bst aliases emb_frag (dead after xg_mfma): 10.42 MB fits in 10.49 MB
  float* bst_g = (float*)emb_frag;
  float* outp = (float*)d_out;

  prep_weights<<<256, 256, 0, stream>>>(wi_f, wi_b, wh_f, wh_b, bf, bbias,
                                        wi_frag, b_p, whn);
  gather_emb<<<(BB * TT_LEN) / 16, 256, 0, stream>>>(x, embed, emb_frag);
  dim3 g1(16, 256, 2);
  xg_mfma<<<g1, 256, 0, stream>>>(emb_frag, (const uint4*)wi_frag, b_p, xg_frag);
  lstm_mfma<<<4, 512, 0, stream>>>(xg_frag, whn, h16g);
  hscore<<<2 * TT_LEN, 64, 0, stream>>>(h16g, w_out, scores_part);
  dp3<<<BB, 128, 0, stream>>>(scores_part, b_out, ast_g, bst_g, lzv);
  marg<<<(BB * TT_LEN) / 4, 256, 0, stream>>>(ast_g, bst_g, lzv, outp);
}